// Round 8
// baseline (176.047 us; speedup 1.0000x reference)
//
#include <hip/hip_runtime.h>
#include <stdint.h>

#define S_LEN 4096
#define DMOD  768
#define NH    12
#define DH    64
#define GG    32
#define NEGBIG (-1e9f)

typedef _Float16 f16;
typedef f16 f16x8 __attribute__((ext_vector_type(8)));
typedef f16 f16x4 __attribute__((ext_vector_type(4)));
typedef float f32x4 __attribute__((ext_vector_type(4)));
typedef float f32x16 __attribute__((ext_vector_type(16)));
typedef uint32_t u32;

// ---------- workspace offsets (bytes), all 256-aligned ----------
#define OFF_H16   ((size_t)0)
#define OFF_WT    ((size_t)6291456)
#define OFF_Q     ((size_t)11010048)
#define OFF_K     ((size_t)17301504)
#define OFF_VT    ((size_t)29884416)
#define OFF_ATT   ((size_t)36175872)
#define OFF_GQO   ((size_t)42467328)
#define OFF_GQL   ((size_t)44040192)

__device__ __forceinline__ void gld_lds16(const void* g, void* l) {
  typedef __attribute__((address_space(3))) u32 lds_u32;
  typedef __attribute__((address_space(1))) u32 glb_u32;
  __builtin_amdgcn_global_load_lds((glb_u32*)(uintptr_t)g,
                                   (lds_u32*)(u32)(uintptr_t)l, 16, 0, 0);
}

// ---------------- prep: weight transpose->f16 + hidden convert ----------------
__global__ __launch_bounds__(256) void prep_kernel(
    const float* __restrict__ hs,
    const float* __restrict__ Wq, const float* __restrict__ Wk,
    const float* __restrict__ Wv, const float* __restrict__ Wo,
    f16* __restrict__ h16, f16* __restrict__ wt)
{
  const int b = blockIdx.x;
  const int t = threadIdx.x;
  if (b < 576) {
    __shared__ float tile[64][65];
    const int w = b / 144, r2 = b % 144;
    const int n0 = (r2 % 12) * 64, k0 = (r2 / 12) * 64;
    const float* W = (w==0) ? Wq : (w==1) ? Wk : (w==2) ? Wv : Wo;
    f16* WT = wt + (size_t)w * DMOD * DMOD;
    #pragma unroll
    for (int rnd = 0; rnd < 4; ++rnd) {
      const int lin = rnd * 1024 + t * 4;
      const int r = lin >> 6, c = lin & 63;
      const float4 vv = *(const float4*)(W + (size_t)(k0 + r) * DMOD + n0 + c);
      tile[r][c+0] = vv.x; tile[r][c+1] = vv.y; tile[r][c+2] = vv.z; tile[r][c+3] = vv.w;
    }
    __syncthreads();
    #pragma unroll
    for (int rnd = 0; rnd < 2; ++rnd) {
      const int lin = rnd * 256 + t;
      const int n = lin >> 3, kc = (lin & 7) * 8;
      f16x8 o;
      #pragma unroll
      for (int j = 0; j < 8; ++j) o[j] = (f16)tile[kc + j][n];
      *(f16x8*)(WT + (size_t)(n0 + n) * DMOD + k0 + kc) = o;
    }
  } else {
    const size_t idx = (size_t)(b - 576) * 2048 + (size_t)t * 8;
    const float4 a = *(const float4*)(hs + idx);
    const float4 c = *(const float4*)(hs + idx + 4);
    f16x8 o;
    o[0]=(f16)a.x; o[1]=(f16)a.y; o[2]=(f16)a.z; o[3]=(f16)a.w;
    o[4]=(f16)c.x; o[5]=(f16)c.y; o[6]=(f16)c.z; o[7]=(f16)c.w;
    *(f16x8*)(h16 + idx) = o;
  }
}

// ---------------- QKV projection GEMM, BK=64, 12 iters, z-merged + XCD-swizzled ----------------
// Fatter K-chunk to amortize the per-iteration skeleton: 8 MFMAs per barrier per
// wave (was 4), 12 barriers (was 24). Same proven sync shape: stage(k+1) ->
// wait-asm(counted vmcnt) -> barrier -> compute(k); mod-3 buffers, depth-1.
// WAR: stage(k+1) writes buf (k-2)%3, last computed two barriers ago.
// Stage = 6 loads/thread (4 A + 2 B) -> in-loop vmcnt(6), tail vmcnt(0).
// LDS layout (BK=64): addr(r,k) = (r>>4)*1024 + (k>>3)*128 + (r&15)*8.
// Stage map: lin -> r = ((lin>>7)<<4)+(lin&15), k = ((lin>>4)&7)*8.
__global__ __launch_bounds__(256) void gemm_qkv(
    const f16* __restrict__ A, const f16* __restrict__ wt,
    const float* __restrict__ bq, const float* __restrict__ bk, const float* __restrict__ bv,
    f16* __restrict__ q16, f16* __restrict__ k16, f16* __restrict__ vt16)
{
  __shared__ __align__(16) f16 At[3][8192];
  __shared__ __align__(16) f16 Bt[3][4096];
  const int bid = blockIdx.x;
  const int w = (bid & 7) * 144 + (bid >> 3);   // XCD-chunked work id (1152%8==0)
  const int x = w % 36, y = w / 36;             // x: n_cat tile, y: m tile
  const int z = x / 12, xn = x % 12;
  const f16* Wt = wt + (size_t)z * DMOD * DMOD;
  const float* bias = (z==0) ? bq : (z==1) ? bk : bv;
  const float scale = (z==0) ? 0.125f : 1.0f;

  const int tid = threadIdx.x;
  const int lane = tid & 63, wid = tid >> 6;
  const int l31 = lane & 31, lhi = lane >> 5;
  const int n0 = xn * 64, m0 = y * 128;
  const int wm = (wid >> 1) * 64, wn = (wid & 1) * 32;

  f32x16 acc[2];
  #pragma unroll
  for (int i=0;i<2;++i)
    #pragma unroll
    for (int e=0;e<16;++e) acc[i][e] = 0.f;

  const f16* Ab = A  + (size_t)m0 * DMOD;
  const f16* Bb = Wt + (size_t)n0 * DMOD;

  auto stage = [&](int buf, int kk) {
    const int k0 = kk * 64;
    #pragma unroll
    for (int j=0;j<4;++j) {                    // A: 128x64 = 1024 transfers
      const int lin = tid + j*256;
      const int r = ((lin>>7)<<4) + (lin&15), kc = ((lin>>4)&7)*8;
      gld_lds16(Ab + (size_t)r*DMOD + k0 + kc, &At[buf][lin*8]);
    }
    #pragma unroll
    for (int j=0;j<2;++j) {                    // B: 64x64 = 512 transfers
      const int lin = tid + j*256;
      const int r = ((lin>>7)<<4) + (lin&15), kc = ((lin>>4)&7)*8;
      gld_lds16(Bb + (size_t)r*DMOD + k0 + kc, &Bt[buf][lin*8]);
    }
  };
  auto compute = [&](int cb) {
    f16x8 af[2][4], bf[4];
    #pragma unroll
    for (int mi=0;mi<2;++mi) {
      const int ro = (wm>>4) + mi*2 + (l31>>4);
      #pragma unroll
      for (int ks=0;ks<4;++ks)
        af[mi][ks] = *(const f16x8*)(&At[cb][ro*1024 + (ks*2+lhi)*128 + (l31&15)*8]);
    }
    {
      const int ro = (wn>>4) + (l31>>4);
      #pragma unroll
      for (int ks=0;ks<4;++ks)
        bf[ks] = *(const f16x8*)(&Bt[cb][ro*1024 + (ks*2+lhi)*128 + (l31&15)*8]);
    }
    #pragma unroll
    for (int mi=0;mi<2;++mi)
      #pragma unroll
      for (int ks=0;ks<4;++ks)
        acc[mi] = __builtin_amdgcn_mfma_f32_32x32x16_f16(af[mi][ks], bf[ks], acc[mi], 0, 0, 0);
  };

  stage(0, 0);
  for (int k = 0; k < 12; ++k) {
    if (k < 11) {
      stage((k+1)%3, k+1);
      asm volatile("s_waitcnt vmcnt(6) lgkmcnt(0)" ::: "memory");
    } else {
      asm volatile("s_waitcnt vmcnt(0) lgkmcnt(0)" ::: "memory");
    }
    __builtin_amdgcn_s_barrier();
    compute(k%3);
  }

  const int col = n0 + wn + l31;
  const float bcol = bias[col];
  const int hh = col >> 6, d = col & 63;
  if (z < 2) {
    f16* outp = (z==0) ? q16 : k16;
    f16* dcol = outp + (size_t)hh * S_LEN * DH + d;
    #pragma unroll
    for (int mi=0;mi<2;++mi) {
      const int rb = m0 + wm + mi*32 + 4*lhi;
      #pragma unroll
      for (int g=0; g<16; ++g) {
        const int srow = rb + (g&3) + 8*(g>>2);
        dcol[(size_t)srow * DH] = (f16)((acc[mi][g] + bcol) * scale);
      }
    }
  } else {
    f16* dcol = vt16 + ((size_t)hh * DH + d) * S_LEN;
    #pragma unroll
    for (int mi=0;mi<2;++mi) {
      const int rb = m0 + wm + mi*32 + 4*lhi;
      #pragma unroll
      for (int q4=0;q4<4;++q4) {
        f16x4 o;
        #pragma unroll
        for (int r=0;r<4;++r) o[r] = (f16)(acc[mi][q4*4+r] + bcol);
        *(f16x4*)(dcol + rb + 8*q4) = o;
      }
    }
  }
}

// ---------------- output GEMM, BK=64, 12 iters, 64x64 tiles, XCD-swizzled ----------------
// Same restructure: 4 MFMAs/barrier/wave (was 2), 12 barriers (was 24).
// Stage = 4 loads/thread (2 A + 2 B) -> in-loop vmcnt(4), tail vmcnt(0).
__global__ __launch_bounds__(256) void gemm_out(
    const f16* __restrict__ A, const f16* __restrict__ Wt,
    const float* __restrict__ bo, float* __restrict__ outp)
{
  __shared__ __align__(16) f16 At[3][4096];
  __shared__ __align__(16) f16 Bt[3][4096];
  const int bid = blockIdx.x;
  const int w = (bid & 7) * 96 + (bid >> 3);
  const int x = w % 12, y = w / 12;
  const int tid = threadIdx.x;
  const int lane = tid & 63, wid = tid >> 6;
  const int l31 = lane & 31, lhi = lane >> 5;
  const int n0 = x * 64, m0 = y * 64;
  const int wm = (wid >> 1) * 32, wn = (wid & 1) * 32;

  f32x16 acc;
  #pragma unroll
  for (int e=0;e<16;++e) acc[e] = 0.f;

  const f16* Ab = A  + (size_t)m0 * DMOD;
  const f16* Bb = Wt + (size_t)n0 * DMOD;

  auto stage = [&](int buf, int kk) {
    const int k0 = kk * 64;
    #pragma unroll
    for (int j=0;j<2;++j) {                    // A: 64x64 = 512 transfers
      const int lin = tid + j*256;
      const int r = ((lin>>7)<<4) + (lin&15), kc = ((lin>>4)&7)*8;
      gld_lds16(Ab + (size_t)r*DMOD + k0 + kc, &At[buf][lin*8]);
    }
    #pragma unroll
    for (int j=0;j<2;++j) {                    // B: 64x64 = 512 transfers
      const int lin = tid + j*256;
      const int r = ((lin>>7)<<4) + (lin&15), kc = ((lin>>4)&7)*8;
      gld_lds16(Bb + (size_t)r*DMOD + k0 + kc, &Bt[buf][lin*8]);
    }
  };
  auto compute = [&](int cb) {
    f16x8 af[4], bf[4];
    const int roA = (wm>>4) + (l31>>4);
    const int roB = (wn>>4) + (l31>>4);
    #pragma unroll
    for (int ks=0;ks<4;++ks) {
      af[ks] = *(const f16x8*)(&At[cb][roA*1024 + (ks*2+lhi)*128 + (l31&15)*8]);
      bf[ks] = *(const f16x8*)(&Bt[cb][roB*1024 + (ks*2+lhi)*128 + (l31&15)*8]);
    }
    #pragma unroll
    for (int ks=0;ks<4;++ks)
      acc = __builtin_amdgcn_mfma_f32_32x32x16_f16(af[ks], bf[ks], acc, 0, 0, 0);
  };

  stage(0, 0);
  for (int k = 0; k < 12; ++k) {
    if (k < 11) {
      stage((k+1)%3, k+1);
      asm volatile("s_waitcnt vmcnt(4) lgkmcnt(0)" ::: "memory");
    } else {
      asm volatile("s_waitcnt vmcnt(0) lgkmcnt(0)" ::: "memory");
    }
    __builtin_amdgcn_s_barrier();
    compute(k%3);
  }

  const int col = n0 + wn + l31;
  const float bcol = bo[col];
  const int rb = m0 + wm + 4*lhi;
  #pragma unroll
  for (int g=0; g<16; ++g) {
    const int srow = rb + (g&3) + 8*(g>>2);
    outp[(size_t)srow * DMOD + col] = acc[g] + bcol;
  }
}

// ---------------- banded attention + global-query partials, XCD-swizzled ----------------
// (round-7 verbatim, known passing)
__global__ __launch_bounds__(256) void band_attn(
    const f16* __restrict__ q16, const f16* __restrict__ k16,
    const f16* __restrict__ vt16, f16* __restrict__ att16,
    float* __restrict__ o_part, float* __restrict__ l_part)
{
  __shared__ __align__(16) f16 Pbuf[4][1280];  // 32x40 f16 per wave
  const int bid = blockIdx.x;
  const int wjob = (bid & 7) * 54 + (bid >> 3);
  const int bx = wjob % 36, h = wjob / 36;
  const int tid = threadIdx.x, lane = tid & 63, wid = tid >> 6;
  const int l31 = lane & 31, lhi = lane >> 5;
  f16* P = &Pbuf[wid][0];

  const bool is_gq = (bx >= 32);
  int gr0 = 0, sp = 0, tcount;
  if (is_gq) {
    sp = (bx - 32) * 4 + wid;
    tcount = 8;
  } else {
    const int sub = bx * 4 + wid;
    if (sub == 0) return;                      // rows 0..31 handled by gq path
    gr0 = sub * 32;
    tcount = 10;
  }

  const f16* qh = q16 + (size_t)h * S_LEN * DH;
  const f16* kh = k16 + (size_t)h * S_LEN * DH;
  const f16* vh = vt16 + (size_t)h * DH * S_LEN;

  // Q A-frags: row = gr0 + l31, k(d) = ks*16 + lhi*8
  f16x8 aq[4];
  #pragma unroll
  for (int ks=0;ks<4;++ks)
    aq[ks] = *(const f16x8*)(qh + (size_t)(gr0 + l31)*DH + ks*16 + lhi*8);

  f32x16 accO[2];
  float lacc[16];
  #pragma unroll
  for (int nt=0;nt<2;++nt)
    #pragma unroll
    for (int e=0;e<16;++e) accO[nt][e] = 0.f;
  #pragma unroll
  for (int g=0;g<16;++g) lacc[g] = 0.f;

  for (int t = 0; t < tcount; ++t) {
    int j0;
    if (is_gq) {
      j0 = sp*256 + t*32;
    } else if (t > 0) {
      j0 = gr0 - 128 + (t-1)*32;
      if (j0 <= 0 || j0 >= S_LEN) continue;    // whole-tile j-clip (always aligned)
    } else {
      j0 = 0;                                  // 32 global key columns
    }
    // K B-frags: col(key) = j0 + l31, k(d) = ks*16 + lhi*8
    f16x8 bk[4];
    #pragma unroll
    for (int ks=0;ks<4;++ks)
      bk[ks] = *(const f16x8*)(kh + (size_t)(j0 + l31)*DH + ks*16 + lhi*8);
    f32x16 sc;
    #pragma unroll
    for (int e=0;e<16;++e) sc[e] = 0.f;
    __builtin_amdgcn_s_setprio(1);
    #pragma unroll
    for (int ks=0;ks<4;++ks)
      sc = __builtin_amdgcn_mfma_f32_32x32x16_f16(aq[ks], bk[ks], sc, 0, 0, 0);
    __builtin_amdgcn_s_setprio(0);
    if (!is_gq && (t == 1 || t == 9)) {        // only edge band tiles need masks
      #pragma unroll
      for (int g=0; g<16; ++g) {
        const int r = (g&3) + 8*(g>>2) + 4*lhi;
        const int e = l31 - r;
        const bool ok = (t == 1) ? (e >= 0) : (e <= 0);
        if (!ok) sc[g] = NEGBIG;
      }
    }
    #pragma unroll
    for (int g=0; g<16; ++g) {
      sc[g] = __expf(sc[g]);
      lacc[g] += sc[g];
    }
    // P: C-layout -> LDS -> A-layout (per-wave scratch; in-order DS queue)
    #pragma unroll
    for (int g=0; g<16; ++g)
      P[((g&3) + 8*(g>>2) + 4*lhi)*40 + l31] = (f16)sc[g];
    asm volatile("s_waitcnt lgkmcnt(0)" ::: "memory");
    f16x8 ap[2];
    #pragma unroll
    for (int ks=0;ks<2;++ks)
      ap[ks] = *(const f16x8*)(P + l31*40 + ks*16 + lhi*8);
    // V B-frags: col(d) = nt*32 + l31, k(key) = ks*16 + lhi*8
    f16x8 bvv[2][2];
    #pragma unroll
    for (int nt=0;nt<2;++nt)
      #pragma unroll
      for (int ks=0;ks<2;++ks)
        bvv[nt][ks] = *(const f16x8*)(vh + (size_t)(nt*32 + l31)*S_LEN + j0 + ks*16 + lhi*8);
    __builtin_amdgcn_s_setprio(1);
    #pragma unroll
    for (int nt=0;nt<2;++nt)
      #pragma unroll
      for (int ks=0;ks<2;++ks)
        accO[nt] = __builtin_amdgcn_mfma_f32_32x32x16_f16(ap[ks], bvv[nt][ks], accO[nt], 0, 0, 0);
    __builtin_amdgcn_s_setprio(0);
  }

  // in-wave reduce of l partials across the 32 column-lanes (bits 0..4)
  #pragma unroll
  for (int g=0; g<16; ++g) {
    float v = lacc[g];
    v += __shfl_xor(v, 1, 64);
    v += __shfl_xor(v, 2, 64);
    v += __shfl_xor(v, 4, 64);
    v += __shfl_xor(v, 8, 64);
    v += __shfl_xor(v, 16, 64);
    lacc[g] = v;
  }

  if (is_gq) {
    const int base = (h*16 + sp)*32;
    #pragma unroll
    for (int g=0; g<16; ++g) {
      const int row = (g&3) + 8*(g>>2) + 4*lhi;
      if (l31 == 0) l_part[base+row] = lacc[g];
      #pragma unroll
      for (int nt=0;nt<2;++nt)
        o_part[(size_t)(base+row)*DH + nt*32 + l31] = accO[nt][g];
    }
  } else {
    #pragma unroll
    for (int g=0; g<16; ++g) {
      const float inv = 1.f / lacc[g];
      const int s = gr0 + (g&3) + 8*(g>>2) + 4*lhi;
      #pragma unroll
      for (int nt=0;nt<2;++nt)
        att16[(size_t)s * DMOD + h*DH + nt*32 + l31] = (f16)(accO[nt][g] * inv);
    }
  }
}

__global__ __launch_bounds__(256) void gq_merge(
    const float* __restrict__ o_part, const float* __restrict__ l_part,
    f16* __restrict__ att16)
{
  const int h = blockIdx.x;
  const int t = threadIdx.x;
  for (int u = t; u < 512; u += 256) {
    const int row = u >> 4, c4 = u & 15;
    float4 s = {0.f,0.f,0.f,0.f};
    float l = 0.f;
    for (int sp=0;sp<16;++sp) {
      const int base = (h*16 + sp)*32 + row;
      const float4 v = *(const float4*)&o_part[(size_t)base*DH + c4*4];
      s.x += v.x; s.y += v.y; s.z += v.z; s.w += v.w;
      l += l_part[base];
    }
    const float inv = 1.f / l;
    f16x4 o;
    o[0] = (f16)(s.x*inv); o[1] = (f16)(s.y*inv);
    o[2] = (f16)(s.z*inv); o[3] = (f16)(s.w*inv);
    *(f16x4*)&att16[(size_t)row * DMOD + h*DH + c4*4] = o;
  }
}

extern "C" void kernel_launch(void* const* d_in, const int* in_sizes, int n_in,
                              void* d_out, int out_size, void* d_ws, size_t ws_size,
                              hipStream_t stream)
{
  const float* hs = (const float*)d_in[0];
  const float* Wq = (const float*)d_in[1];
  const float* bq = (const float*)d_in[2];
  const float* Wk = (const float*)d_in[3];
  const float* bk = (const float*)d_in[4];
  const float* Wv = (const float*)d_in[5];
  const float* bv = (const float*)d_in[6];
  const float* Wo = (const float*)d_in[7];
  const float* bo = (const float*)d_in[8];
  float* out = (float*)d_out;
  char* ws = (char*)d_ws;
  f16* h16  = (f16*)(ws + OFF_H16);
  f16* wt   = (f16*)(ws + OFF_WT);
  f16* q16  = (f16*)(ws + OFF_Q);
  f16* k16  = (f16*)(ws + OFF_K);
  f16* vt16 = (f16*)(ws + OFF_VT);
  f16* att16= (f16*)(ws + OFF_ATT);
  float* gqo = (float*)(ws + OFF_GQO);
  float* gql = (float*)(ws + OFF_GQL);

  prep_kernel<<<2112, 256, 0, stream>>>(hs, Wq, Wk, Wv, Wo, h16, wt);
  gemm_qkv<<<1152, 256, 0, stream>>>(h16, wt, bq, bk, bv, q16, k16, vt16);
  band_attn<<<432, 256, 0, stream>>>(q16, k16, vt16, att16, gqo, gql);
  gq_merge<<<12, 256, 0, stream>>>(gqo, gql, att16);
  gemm_out<<<768, 256, 0, stream>>>(att16, wt + (size_t)3*DMOD*DMOD, bo, out);
}

// Round 9
// 169.834 us; speedup vs baseline: 1.0366x; 1.0366x over previous
//
#include <hip/hip_runtime.h>
#include <stdint.h>

#define S_LEN 4096
#define DMOD  768
#define NH    12
#define DH    64
#define GG    32
#define NEGBIG (-1e9f)

typedef _Float16 f16;
typedef f16 f16x8 __attribute__((ext_vector_type(8)));
typedef f16 f16x4 __attribute__((ext_vector_type(4)));
typedef float f32x4 __attribute__((ext_vector_type(4)));
typedef float f32x16 __attribute__((ext_vector_type(16)));
typedef uint32_t u32;

// ---------- workspace offsets (bytes), all 256-aligned ----------
#define OFF_H16   ((size_t)0)
#define OFF_WT    ((size_t)6291456)
#define OFF_Q     ((size_t)11010048)
#define OFF_K     ((size_t)17301504)
#define OFF_VT    ((size_t)29884416)
#define OFF_ATT   ((size_t)36175872)
#define OFF_GQO   ((size_t)42467328)
#define OFF_GQL   ((size_t)44040192)

__device__ __forceinline__ void gld_lds16(const void* g, void* l) {
  typedef __attribute__((address_space(3))) u32 lds_u32;
  typedef __attribute__((address_space(1))) u32 glb_u32;
  __builtin_amdgcn_global_load_lds((glb_u32*)(uintptr_t)g,
                                   (lds_u32*)(u32)(uintptr_t)l, 16, 0, 0);
}

// ---------------- prep: weight transpose->f16 + hidden convert ----------------
__global__ __launch_bounds__(256) void prep_kernel(
    const float* __restrict__ hs,
    const float* __restrict__ Wq, const float* __restrict__ Wk,
    const float* __restrict__ Wv, const float* __restrict__ Wo,
    f16* __restrict__ h16, f16* __restrict__ wt)
{
  const int b = blockIdx.x;
  const int t = threadIdx.x;
  if (b < 576) {
    __shared__ float tile[64][65];
    const int w = b / 144, r2 = b % 144;
    const int n0 = (r2 % 12) * 64, k0 = (r2 / 12) * 64;
    const float* W = (w==0) ? Wq : (w==1) ? Wk : (w==2) ? Wv : Wo;
    f16* WT = wt + (size_t)w * DMOD * DMOD;
    #pragma unroll
    for (int rnd = 0; rnd < 4; ++rnd) {
      const int lin = rnd * 1024 + t * 4;
      const int r = lin >> 6, c = lin & 63;
      const float4 vv = *(const float4*)(W + (size_t)(k0 + r) * DMOD + n0 + c);
      tile[r][c+0] = vv.x; tile[r][c+1] = vv.y; tile[r][c+2] = vv.z; tile[r][c+3] = vv.w;
    }
    __syncthreads();
    #pragma unroll
    for (int rnd = 0; rnd < 2; ++rnd) {
      const int lin = rnd * 256 + t;
      const int n = lin >> 3, kc = (lin & 7) * 8;
      f16x8 o;
      #pragma unroll
      for (int j = 0; j < 8; ++j) o[j] = (f16)tile[kc + j][n];
      *(f16x8*)(WT + (size_t)(n0 + n) * DMOD + k0 + kc) = o;
    }
  } else {
    const size_t idx = (size_t)(b - 576) * 2048 + (size_t)t * 8;
    const float4 a = *(const float4*)(hs + idx);
    const float4 c = *(const float4*)(hs + idx + 4);
    f16x8 o;
    o[0]=(f16)a.x; o[1]=(f16)a.y; o[2]=(f16)a.z; o[3]=(f16)a.w;
    o[4]=(f16)c.x; o[5]=(f16)c.y; o[6]=(f16)c.z; o[7]=(f16)c.w;
    *(f16x8*)(h16 + idx) = o;
  }
}

// ---------------- QKV projection GEMM: Round-2 body (42.6 us, passing) + XCD swizzle ----------
// 128x128 tile, triple-buffered LDS, stage(nxt)->vmcnt(4)->barrier->compute(cur),
// 8 MFMA/wave/iter. Grid 576 1-D; w=(bid&7)*72+(bid>>3) bijective (576%8==0),
// y-major decode: each XCD owns 4 contiguous A-panels x all 18 (z,x) tiles ->
// A fetched ~once per XCD, B (3.5 MB) L2-resident.
__global__ __launch_bounds__(256) void gemm_qkv(
    const f16* __restrict__ A, const f16* __restrict__ wt,
    const float* __restrict__ bq, const float* __restrict__ bk, const float* __restrict__ bv,
    f16* __restrict__ q16, f16* __restrict__ k16, f16* __restrict__ vt16)
{
  __shared__ __align__(16) f16 At[3][4096];
  __shared__ __align__(16) f16 Bt[3][4096];
  const int bid = blockIdx.x;
  const int w = (bid & 7) * 72 + (bid >> 3);
  const int y = w / 18, r18 = w % 18;
  const int z = r18 / 6, x = r18 % 6;
  const f16* Wt = wt + (size_t)z * DMOD * DMOD;
  const float* bias = (z==0) ? bq : (z==1) ? bk : bv;
  const float scale = (z==0) ? 0.125f : 1.0f;

  const int tid = threadIdx.x;
  const int lane = tid & 63, wid = tid >> 6;
  const int l31 = lane & 31, lhi = lane >> 5;
  const int n0 = x * 128, m0 = y * 128;
  const int wm = (wid >> 1) * 64, wn = (wid & 1) * 64;

  f32x16 acc[2][2];
  #pragma unroll
  for (int i=0;i<2;++i)
    #pragma unroll
    for (int j=0;j<2;++j)
      #pragma unroll
      for (int e=0;e<16;++e) acc[i][j][e] = 0.f;

  const int lin0 = tid, lin1 = tid + 256;
  const int ar0 = ((lin0>>6)<<4) + (lin0&15), ac0 = ((lin0>>4)&3)*8;
  const int ar1 = ((lin1>>6)<<4) + (lin1&15), ac1 = ((lin1>>4)&3)*8;
  const f16* Ab = A  + (size_t)m0 * DMOD;
  const f16* Bb = Wt + (size_t)n0 * DMOD;

  // prologue: stage k-chunk 0 into buffer 0
  gld_lds16(Ab + (size_t)ar0*DMOD + ac0, &At[0][lin0*8]);
  gld_lds16(Ab + (size_t)ar1*DMOD + ac1, &At[0][lin1*8]);
  gld_lds16(Bb + (size_t)ar0*DMOD + ac0, &Bt[0][lin0*8]);
  gld_lds16(Bb + (size_t)ar1*DMOD + ac1, &Bt[0][lin1*8]);

  int cur = 0;
  #pragma unroll 3
  for (int k = 0; k < 24; ++k) {
    const int nxt = (cur == 2) ? 0 : cur + 1;
    if (k < 23) {
      const int k0 = (k + 1) * 32;
      gld_lds16(Ab + (size_t)ar0*DMOD + k0 + ac0, &At[nxt][lin0*8]);
      gld_lds16(Ab + (size_t)ar1*DMOD + k0 + ac1, &At[nxt][lin1*8]);
      gld_lds16(Bb + (size_t)ar0*DMOD + k0 + ac0, &Bt[nxt][lin0*8]);
      gld_lds16(Bb + (size_t)ar1*DMOD + k0 + ac1, &Bt[nxt][lin1*8]);
      asm volatile("s_waitcnt vmcnt(4) lgkmcnt(0)" ::: "memory");
    } else {
      asm volatile("s_waitcnt vmcnt(0) lgkmcnt(0)" ::: "memory");
    }
    __builtin_amdgcn_s_barrier();
    // A-frag (32x32x16): row = R0 + l31, k = ks*16 + lhi*8
    // LDS hw addr(r,k) = (r>>4)*512 + (k>>3)*128 + (r&15)*8
    f16x8 af[2][2], bf[2][2];
    #pragma unroll
    for (int mi=0;mi<2;++mi)
      #pragma unroll
      for (int ks=0;ks<2;++ks) {
        const int ro = (wm>>4) + mi*2 + (l31>>4);
        af[mi][ks] = *(const f16x8*)(&At[cur][ro*512 + (ks*2+lhi)*128 + (l31&15)*8]);
      }
    #pragma unroll
    for (int nj=0;nj<2;++nj)
      #pragma unroll
      for (int ks=0;ks<2;++ks) {
        const int ro = (wn>>4) + nj*2 + (l31>>4);
        bf[nj][ks] = *(const f16x8*)(&Bt[cur][ro*512 + (ks*2+lhi)*128 + (l31&15)*8]);
      }
    #pragma unroll
    for (int mi=0;mi<2;++mi)
      #pragma unroll
      for (int nj=0;nj<2;++nj) {
        acc[mi][nj] = __builtin_amdgcn_mfma_f32_32x32x16_f16(af[mi][0], bf[nj][0], acc[mi][nj], 0, 0, 0);
        acc[mi][nj] = __builtin_amdgcn_mfma_f32_32x32x16_f16(af[mi][1], bf[nj][1], acc[mi][nj], 0, 0, 0);
      }
    cur = nxt;
  }

  if (z < 2) {
    f16* outp = (z==0) ? q16 : k16;
    #pragma unroll
    for (int nj=0;nj<2;++nj) {
      const int col = n0 + wn + nj*32 + l31;
      const float bcol = bias[col];
      const int hh = col >> 6, d = col & 63;
      f16* dcol = outp + (size_t)hh * S_LEN * DH + d;
      #pragma unroll
      for (int mi=0;mi<2;++mi) {
        const int rb = m0 + wm + mi*32 + 4*lhi;
        #pragma unroll
        for (int g=0; g<16; ++g) {
          const int srow = rb + (g&3) + 8*(g>>2);
          dcol[(size_t)srow * DH] = (f16)((acc[mi][nj][g] + bcol) * scale);
        }
      }
    }
  } else {
    #pragma unroll
    for (int nj=0;nj<2;++nj) {
      const int col = n0 + wn + nj*32 + l31;
      const float bcol = bias[col];
      const int hh = col >> 6, d = col & 63;
      f16* dcol = vt16 + ((size_t)hh * DH + d) * S_LEN;
      #pragma unroll
      for (int mi=0;mi<2;++mi) {
        const int rb = m0 + wm + mi*32 + 4*lhi;
        #pragma unroll
        for (int q4=0;q4<4;++q4) {
          f16x4 o;
          #pragma unroll
          for (int r=0;r<4;++r) o[r] = (f16)(acc[mi][nj][q4*4+r] + bcol);
          *(f16x4*)(dcol + rb + 8*q4) = o;
        }
      }
    }
  }
}

// ---------------- output GEMM, BK=64, 12 iters, 64x64 tiles, XCD-swizzled ----------------
// (round-8 verbatim, known passing)
__global__ __launch_bounds__(256) void gemm_out(
    const f16* __restrict__ A, const f16* __restrict__ Wt,
    const float* __restrict__ bo, float* __restrict__ outp)
{
  __shared__ __align__(16) f16 At[3][4096];
  __shared__ __align__(16) f16 Bt[3][4096];
  const int bid = blockIdx.x;
  const int w = (bid & 7) * 96 + (bid >> 3);
  const int x = w % 12, y = w / 12;
  const int tid = threadIdx.x;
  const int lane = tid & 63, wid = tid >> 6;
  const int l31 = lane & 31, lhi = lane >> 5;
  const int n0 = x * 64, m0 = y * 64;
  const int wm = (wid >> 1) * 32, wn = (wid & 1) * 32;

  f32x16 acc;
  #pragma unroll
  for (int e=0;e<16;++e) acc[e] = 0.f;

  const f16* Ab = A  + (size_t)m0 * DMOD;
  const f16* Bb = Wt + (size_t)n0 * DMOD;

  auto stage = [&](int buf, int kk) {
    const int k0 = kk * 64;
    #pragma unroll
    for (int j=0;j<2;++j) {                    // A: 64x64 = 512 transfers
      const int lin = tid + j*256;
      const int r = ((lin>>7)<<4) + (lin&15), kc = ((lin>>4)&7)*8;
      gld_lds16(Ab + (size_t)r*DMOD + k0 + kc, &At[buf][lin*8]);
    }
    #pragma unroll
    for (int j=0;j<2;++j) {                    // B: 64x64 = 512 transfers
      const int lin = tid + j*256;
      const int r = ((lin>>7)<<4) + (lin&15), kc = ((lin>>4)&7)*8;
      gld_lds16(Bb + (size_t)r*DMOD + k0 + kc, &Bt[buf][lin*8]);
    }
  };
  auto compute = [&](int cb) {
    f16x8 af[4], bf[4];
    const int roA = (wm>>4) + (l31>>4);
    const int roB = (wn>>4) + (l31>>4);
    #pragma unroll
    for (int ks=0;ks<4;++ks) {
      af[ks] = *(const f16x8*)(&At[cb][roA*1024 + (ks*2+lhi)*128 + (l31&15)*8]);
      bf[ks] = *(const f16x8*)(&Bt[cb][roB*1024 + (ks*2+lhi)*128 + (l31&15)*8]);
    }
    #pragma unroll
    for (int ks=0;ks<4;++ks)
      acc = __builtin_amdgcn_mfma_f32_32x32x16_f16(af[ks], bf[ks], acc, 0, 0, 0);
  };

  stage(0, 0);
  for (int k = 0; k < 12; ++k) {
    if (k < 11) {
      stage((k+1)%3, k+1);
      asm volatile("s_waitcnt vmcnt(4) lgkmcnt(0)" ::: "memory");
    } else {
      asm volatile("s_waitcnt vmcnt(0) lgkmcnt(0)" ::: "memory");
    }
    __builtin_amdgcn_s_barrier();
    compute(k%3);
  }

  const int col = n0 + wn + l31;
  const float bcol = bo[col];
  const int rb = m0 + wm + 4*lhi;
  #pragma unroll
  for (int g=0; g<16; ++g) {
    const int srow = rb + (g&3) + 8*(g>>2);
    outp[(size_t)srow * DMOD + col] = acc[g] + bcol;
  }
}

// ---------------- banded attention + global-query partials, XCD-swizzled ----------------
// (round-8 verbatim, known passing)
__global__ __launch_bounds__(256) void band_attn(
    const f16* __restrict__ q16, const f16* __restrict__ k16,
    const f16* __restrict__ vt16, f16* __restrict__ att16,
    float* __restrict__ o_part, float* __restrict__ l_part)
{
  __shared__ __align__(16) f16 Pbuf[4][1280];  // 32x40 f16 per wave
  const int bid = blockIdx.x;
  const int wjob = (bid & 7) * 54 + (bid >> 3);
  const int bx = wjob % 36, h = wjob / 36;
  const int tid = threadIdx.x, lane = tid & 63, wid = tid >> 6;
  const int l31 = lane & 31, lhi = lane >> 5;
  f16* P = &Pbuf[wid][0];

  const bool is_gq = (bx >= 32);
  int gr0 = 0, sp = 0, tcount;
  if (is_gq) {
    sp = (bx - 32) * 4 + wid;
    tcount = 8;
  } else {
    const int sub = bx * 4 + wid;
    if (sub == 0) return;                      // rows 0..31 handled by gq path
    gr0 = sub * 32;
    tcount = 10;
  }

  const f16* qh = q16 + (size_t)h * S_LEN * DH;
  const f16* kh = k16 + (size_t)h * S_LEN * DH;
  const f16* vh = vt16 + (size_t)h * DH * S_LEN;

  // Q A-frags: row = gr0 + l31, k(d) = ks*16 + lhi*8
  f16x8 aq[4];
  #pragma unroll
  for (int ks=0;ks<4;++ks)
    aq[ks] = *(const f16x8*)(qh + (size_t)(gr0 + l31)*DH + ks*16 + lhi*8);

  f32x16 accO[2];
  float lacc[16];
  #pragma unroll
  for (int nt=0;nt<2;++nt)
    #pragma unroll
    for (int e=0;e<16;++e) accO[nt][e] = 0.f;
  #pragma unroll
  for (int g=0;g<16;++g) lacc[g] = 0.f;

  for (int t = 0; t < tcount; ++t) {
    int j0;
    if (is_gq) {
      j0 = sp*256 + t*32;
    } else if (t > 0) {
      j0 = gr0 - 128 + (t-1)*32;
      if (j0 <= 0 || j0 >= S_LEN) continue;    // whole-tile j-clip (always aligned)
    } else {
      j0 = 0;                                  // 32 global key columns
    }
    // K B-frags: col(key) = j0 + l31, k(d) = ks*16 + lhi*8
    f16x8 bk[4];
    #pragma unroll
    for (int ks=0;ks<4;++ks)
      bk[ks] = *(const f16x8*)(kh + (size_t)(j0 + l31)*DH + ks*16 + lhi*8);
    f32x16 sc;
    #pragma unroll
    for (int e=0;e<16;++e) sc[e] = 0.f;
    __builtin_amdgcn_s_setprio(1);
    #pragma unroll
    for (int ks=0;ks<4;++ks)
      sc = __builtin_amdgcn_mfma_f32_32x32x16_f16(aq[ks], bk[ks], sc, 0, 0, 0);
    __builtin_amdgcn_s_setprio(0);
    if (!is_gq && (t == 1 || t == 9)) {        // only edge band tiles need masks
      #pragma unroll
      for (int g=0; g<16; ++g) {
        const int r = (g&3) + 8*(g>>2) + 4*lhi;
        const int e = l31 - r;
        const bool ok = (t == 1) ? (e >= 0) : (e <= 0);
        if (!ok) sc[g] = NEGBIG;
      }
    }
    #pragma unroll
    for (int g=0; g<16; ++g) {
      sc[g] = __expf(sc[g]);
      lacc[g] += sc[g];
    }
    // P: C-layout -> LDS -> A-layout (per-wave scratch; in-order DS queue)
    #pragma unroll
    for (int g=0; g<16; ++g)
      P[((g&3) + 8*(g>>2) + 4*lhi)*40 + l31] = (f16)sc[g];
    asm volatile("s_waitcnt lgkmcnt(0)" ::: "memory");
    f16x8 ap[2];
    #pragma unroll
    for (int ks=0;ks<2;++ks)
      ap[ks] = *(const f16x8*)(P + l31*40 + ks*16 + lhi*8);
    // V B-frags: col(d) = nt*32 + l31, k(key) = ks*16 + lhi*8
    f16x8 bvv[2][2];
    #pragma unroll
    for (int nt=0;nt<2;++nt)
      #pragma unroll
      for (int ks=0;ks<2;++ks)
        bvv[nt][ks] = *(const f16x8*)(vh + (size_t)(nt*32 + l31)*S_LEN + j0 + ks*16 + lhi*8);
    __builtin_amdgcn_s_setprio(1);
    #pragma unroll
    for (int nt=0;nt<2;++nt)
      #pragma unroll
      for (int ks=0;ks<2;++ks)
        accO[nt] = __builtin_amdgcn_mfma_f32_32x32x16_f16(ap[ks], bvv[nt][ks], accO[nt], 0, 0, 0);
    __builtin_amdgcn_s_setprio(0);
  }

  // in-wave reduce of l partials across the 32 column-lanes (bits 0..4)
  #pragma unroll
  for (int g=0; g<16; ++g) {
    float v = lacc[g];
    v += __shfl_xor(v, 1, 64);
    v += __shfl_xor(v, 2, 64);
    v += __shfl_xor(v, 4, 64);
    v += __shfl_xor(v, 8, 64);
    v += __shfl_xor(v, 16, 64);
    lacc[g] = v;
  }

  if (is_gq) {
    const int base = (h*16 + sp)*32;
    #pragma unroll
    for (int g=0; g<16; ++g) {
      const int row = (g&3) + 8*(g>>2) + 4*lhi;
      if (l31 == 0) l_part[base+row] = lacc[g];
      #pragma unroll
      for (int nt=0;nt<2;++nt)
        o_part[(size_t)(base+row)*DH + nt*32 + l31] = accO[nt][g];
    }
  } else {
    #pragma unroll
    for (int g=0; g<16; ++g) {
      const float inv = 1.f / lacc[g];
      const int s = gr0 + (g&3) + 8*(g>>2) + 4*lhi;
      #pragma unroll
      for (int nt=0;nt<2;++nt)
        att16[(size_t)s * DMOD + h*DH + nt*32 + l31] = (f16)(accO[nt][g] * inv);
    }
  }
}

__global__ __launch_bounds__(256) void gq_merge(
    const float* __restrict__ o_part, const float* __restrict__ l_part,
    f16* __restrict__ att16)
{
  const int h = blockIdx.x;
  const int t = threadIdx.x;
  for (int u = t; u < 512; u += 256) {
    const int row = u >> 4, c4 = u & 15;
    float4 s = {0.f,0.f,0.f,0.f};
    float l = 0.f;
    for (int sp=0;sp<16;++sp) {
      const int base = (h*16 + sp)*32 + row;
      const float4 v = *(const float4*)&o_part[(size_t)base*DH + c4*4];
      s.x += v.x; s.y += v.y; s.z += v.z; s.w += v.w;
      l += l_part[base];
    }
    const float inv = 1.f / l;
    f16x4 o;
    o[0] = (f16)(s.x*inv); o[1] = (f16)(s.y*inv);
    o[2] = (f16)(s.z*inv); o[3] = (f16)(s.w*inv);
    *(f16x4*)&att16[(size_t)row * DMOD + h*DH + c4*4] = o;
  }
}

extern "C" void kernel_launch(void* const* d_in, const int* in_sizes, int n_in,
                              void* d_out, int out_size, void* d_ws, size_t ws_size,
                              hipStream_t stream)
{
  const float* hs = (const float*)d_in[0];
  const float* Wq = (const float*)d_in[1];
  const float* bq = (const float*)d_in[2];
  const float* Wk = (const float*)d_in[3];
  const float* bk = (const float*)d_in[4];
  const float* Wv = (const float*)d_in[5];
  const float* bv = (const float*)d_in[6];
  const float* Wo = (const float*)d_in[7];
  const float* bo = (const float*)d_in[8];
  float* out = (float*)d_out;
  char* ws = (char*)d_ws;
  f16* h16  = (f16*)(ws + OFF_H16);
  f16* wt   = (f16*)(ws + OFF_WT);
  f16* q16  = (f16*)(ws + OFF_Q);
  f16* k16  = (f16*)(ws + OFF_K);
  f16* vt16 = (f16*)(ws + OFF_VT);
  f16* att16= (f16*)(ws + OFF_ATT);
  float* gqo = (float*)(ws + OFF_GQO);
  float* gql = (float*)(ws + OFF_GQL);

  prep_kernel<<<2112, 256, 0, stream>>>(hs, Wq, Wk, Wv, Wo, h16, wt);
  gemm_qkv<<<576, 256, 0, stream>>>(h16, wt, bq, bk, bv, q16, k16, vt16);
  band_attn<<<432, 256, 0, stream>>>(q16, k16, vt16, att16, gqo, gql);
  gq_merge<<<12, 256, 0, stream>>>(gqo, gql, att16);
  gemm_out<<<768, 256, 0, stream>>>(att16, wt + (size_t)3*DMOD*DMOD, bo, out);
}

// Round 11
// 169.788 us; speedup vs baseline: 1.0369x; 1.0003x over previous
//
#include <hip/hip_runtime.h>
#include <stdint.h>

#define S_LEN 4096
#define DMOD  768
#define NH    12
#define DH    64
#define GG    32
#define NEGBIG (-1e9f)

typedef _Float16 f16;
typedef f16 f16x8 __attribute__((ext_vector_type(8)));
typedef f16 f16x4 __attribute__((ext_vector_type(4)));
typedef float f32x4 __attribute__((ext_vector_type(4)));
typedef float f32x16 __attribute__((ext_vector_type(16)));
typedef uint32_t u32;

// ---------- workspace offsets (bytes), all 256-aligned ----------
#define OFF_H16   ((size_t)0)
#define OFF_WT    ((size_t)6291456)
#define OFF_Q     ((size_t)11010048)
#define OFF_K     ((size_t)17301504)
#define OFF_VT    ((size_t)29884416)
#define OFF_ATT   ((size_t)36175872)
#define OFF_GQO   ((size_t)42467328)
#define OFF_GQL   ((size_t)44040192)

__device__ __forceinline__ void gld_lds16(const void* g, void* l) {
  typedef __attribute__((address_space(3))) u32 lds_u32;
  typedef __attribute__((address_space(1))) u32 glb_u32;
  __builtin_amdgcn_global_load_lds((glb_u32*)(uintptr_t)g,
                                   (lds_u32*)(u32)(uintptr_t)l, 16, 0, 0);
}

// ---------------- prep: weight transpose->f16 + hidden convert ----------------
__global__ __launch_bounds__(256) void prep_kernel(
    const float* __restrict__ hs,
    const float* __restrict__ Wq, const float* __restrict__ Wk,
    const float* __restrict__ Wv, const float* __restrict__ Wo,
    f16* __restrict__ h16, f16* __restrict__ wt)
{
  const int b = blockIdx.x;
  const int t = threadIdx.x;
  if (b < 576) {
    __shared__ float tile[64][65];
    const int w = b / 144, r2 = b % 144;
    const int n0 = (r2 % 12) * 64, k0 = (r2 / 12) * 64;
    const float* W = (w==0) ? Wq : (w==1) ? Wk : (w==2) ? Wv : Wo;
    f16* WT = wt + (size_t)w * DMOD * DMOD;
    #pragma unroll
    for (int rnd = 0; rnd < 4; ++rnd) {
      const int lin = rnd * 1024 + t * 4;
      const int r = lin >> 6, c = lin & 63;
      const float4 vv = *(const float4*)(W + (size_t)(k0 + r) * DMOD + n0 + c);
      tile[r][c+0] = vv.x; tile[r][c+1] = vv.y; tile[r][c+2] = vv.z; tile[r][c+3] = vv.w;
    }
    __syncthreads();
    #pragma unroll
    for (int rnd = 0; rnd < 2; ++rnd) {
      const int lin = rnd * 256 + t;
      const int n = lin >> 3, kc = (lin & 7) * 8;
      f16x8 o;
      #pragma unroll
      for (int j = 0; j < 8; ++j) o[j] = (f16)tile[kc + j][n];
      *(f16x8*)(WT + (size_t)(n0 + n) * DMOD + k0 + kc) = o;
    }
  } else {
    const size_t idx = (size_t)(b - 576) * 2048 + (size_t)t * 8;
    const float4 a = *(const float4*)(hs + idx);
    const float4 c = *(const float4*)(hs + idx + 4);
    f16x8 o;
    o[0]=(f16)a.x; o[1]=(f16)a.y; o[2]=(f16)a.z; o[3]=(f16)a.w;
    o[4]=(f16)c.x; o[5]=(f16)c.y; o[6]=(f16)c.z; o[7]=(f16)c.w;
    *(f16x8*)(h16 + idx) = o;
  }
}

// ---------------- QKV projection GEMM: 128x128, depth-3 prefetch, 5 buffers ----------------
// Motion-proof shape: stage(k+3) -> wait-asm(counted) -> barrier -> compute(k).
// vmcnt: 16 outstanding after issue; vmcnt(12) retires stage k (3 compute phases
// ~500 cyc after issue -> covers L2-warm load latency). Tail 8/4/0.
// WAR: buf (k+3)%5 last read by compute(k-2); separated by asm-fence(k-1) +
// barrier(k-1) -- same one-barrier discipline as the passing r4/r8/r9 kernels.
// XCD swizzle (r9, FETCH 71->22 MB): w=(bid&7)*72+(bid>>3), y-major decode.
__global__ __launch_bounds__(256) void gemm_qkv(
    const f16* __restrict__ A, const f16* __restrict__ wt,
    const float* __restrict__ bq, const float* __restrict__ bk, const float* __restrict__ bv,
    f16* __restrict__ q16, f16* __restrict__ k16, f16* __restrict__ vt16)
{
  __shared__ __align__(16) f16 At[5][4096];
  __shared__ __align__(16) f16 Bt[5][4096];
  const int bid = blockIdx.x;
  const int w = (bid & 7) * 72 + (bid >> 3);
  const int y = w / 18, r18 = w % 18;
  const int z = r18 / 6, x = r18 % 6;
  const f16* Wt = wt + (size_t)z * DMOD * DMOD;
  const float* bias = (z==0) ? bq : (z==1) ? bk : bv;
  const float scale = (z==0) ? 0.125f : 1.0f;

  const int tid = threadIdx.x;
  const int lane = tid & 63, wid = tid >> 6;
  const int l31 = lane & 31, lhi = lane >> 5;
  const int n0 = x * 128, m0 = y * 128;
  const int wm = (wid >> 1) * 64, wn = (wid & 1) * 64;

  f32x16 acc[2][2];
  #pragma unroll
  for (int i=0;i<2;++i)
    #pragma unroll
    for (int j=0;j<2;++j)
      #pragma unroll
      for (int e=0;e<16;++e) acc[i][j][e] = 0.f;

  const int lin0 = tid, lin1 = tid + 256;
  const int ar0 = ((lin0>>6)<<4) + (lin0&15), ac0 = ((lin0>>4)&3)*8;
  const int ar1 = ((lin1>>6)<<4) + (lin1&15), ac1 = ((lin1>>4)&3)*8;
  const f16* Ab = A  + (size_t)m0 * DMOD;
  const f16* Bb = Wt + (size_t)n0 * DMOD;

  auto stage = [&](int buf, int kk) {
    const int k0 = kk * 32;
    gld_lds16(Ab + (size_t)ar0*DMOD + k0 + ac0, &At[buf][lin0*8]);
    gld_lds16(Ab + (size_t)ar1*DMOD + k0 + ac1, &At[buf][lin1*8]);
    gld_lds16(Bb + (size_t)ar0*DMOD + k0 + ac0, &Bt[buf][lin0*8]);
    gld_lds16(Bb + (size_t)ar1*DMOD + k0 + ac1, &Bt[buf][lin1*8]);
  };
  auto compute = [&](int cb) {
    // LDS hw addr(r,k) = (r>>4)*512 + (k>>3)*128 + (r&15)*8
    f16x8 af[2][2], bf[2][2];
    #pragma unroll
    for (int mi=0;mi<2;++mi)
      #pragma unroll
      for (int ks=0;ks<2;++ks) {
        const int ro = (wm>>4) + mi*2 + (l31>>4);
        af[mi][ks] = *(const f16x8*)(&At[cb][ro*512 + (ks*2+lhi)*128 + (l31&15)*8]);
      }
    #pragma unroll
    for (int nj=0;nj<2;++nj)
      #pragma unroll
      for (int ks=0;ks<2;++ks) {
        const int ro = (wn>>4) + nj*2 + (l31>>4);
        bf[nj][ks] = *(const f16x8*)(&Bt[cb][ro*512 + (ks*2+lhi)*128 + (l31&15)*8]);
      }
    #pragma unroll
    for (int mi=0;mi<2;++mi)
      #pragma unroll
      for (int nj=0;nj<2;++nj) {
        acc[mi][nj] = __builtin_amdgcn_mfma_f32_32x32x16_f16(af[mi][0], bf[nj][0], acc[mi][nj], 0, 0, 0);
        acc[mi][nj] = __builtin_amdgcn_mfma_f32_32x32x16_f16(af[mi][1], bf[nj][1], acc[mi][nj], 0, 0, 0);
      }
  };

  stage(0, 0);
  stage(1, 1);
  stage(2, 2);
  for (int k = 0; k < 24; ++k) {
    if (k < 21) {
      stage((k+3)%5, k+3);
      asm volatile("s_waitcnt vmcnt(12) lgkmcnt(0)" ::: "memory");
    } else if (k == 21) {
      asm volatile("s_waitcnt vmcnt(8) lgkmcnt(0)" ::: "memory");
    } else if (k == 22) {
      asm volatile("s_waitcnt vmcnt(4) lgkmcnt(0)" ::: "memory");
    } else {
      asm volatile("s_waitcnt vmcnt(0) lgkmcnt(0)" ::: "memory");
    }
    __builtin_amdgcn_s_barrier();
    compute(k%5);
  }

  if (z < 2) {
    f16* outp = (z==0) ? q16 : k16;
    #pragma unroll
    for (int nj=0;nj<2;++nj) {
      const int col = n0 + wn + nj*32 + l31;
      const float bcol = bias[col];
      const int hh = col >> 6, d = col & 63;
      f16* dcol = outp + (size_t)hh * S_LEN * DH + d;
      #pragma unroll
      for (int mi=0;mi<2;++mi) {
        const int rb = m0 + wm + mi*32 + 4*lhi;
        #pragma unroll
        for (int g=0; g<16; ++g) {
          const int srow = rb + (g&3) + 8*(g>>2);
          dcol[(size_t)srow * DH] = (f16)((acc[mi][nj][g] + bcol) * scale);
        }
      }
    }
  } else {
    #pragma unroll
    for (int nj=0;nj<2;++nj) {
      const int col = n0 + wn + nj*32 + l31;
      const float bcol = bias[col];
      const int hh = col >> 6, d = col & 63;
      f16* dcol = vt16 + ((size_t)hh * DH + d) * S_LEN;
      #pragma unroll
      for (int mi=0;mi<2;++mi) {
        const int rb = m0 + wm + mi*32 + 4*lhi;
        #pragma unroll
        for (int q4=0;q4<4;++q4) {
          f16x4 o;
          #pragma unroll
          for (int r=0;r<4;++r) o[r] = (f16)(acc[mi][nj][q4*4+r] + bcol);
          *(f16x4*)(dcol + rb + 8*q4) = o;
        }
      }
    }
  }
}

// ---------------- output GEMM, BK=64, 12 iters, 64x64 tiles, XCD-swizzled ----------------
// (round-9 verbatim, known passing)
__global__ __launch_bounds__(256) void gemm_out(
    const f16* __restrict__ A, const f16* __restrict__ Wt,
    const float* __restrict__ bo, float* __restrict__ outp)
{
  __shared__ __align__(16) f16 At[3][4096];
  __shared__ __align__(16) f16 Bt[3][4096];
  const int bid = blockIdx.x;
  const int w = (bid & 7) * 96 + (bid >> 3);
  const int x = w % 12, y = w / 12;
  const int tid = threadIdx.x;
  const int lane = tid & 63, wid = tid >> 6;
  const int l31 = lane & 31, lhi = lane >> 5;
  const int n0 = x * 64, m0 = y * 64;
  const int wm = (wid >> 1) * 32, wn = (wid & 1) * 32;

  f32x16 acc;
  #pragma unroll
  for (int e=0;e<16;++e) acc[e] = 0.f;

  const f16* Ab = A  + (size_t)m0 * DMOD;
  const f16* Bb = Wt + (size_t)n0 * DMOD;

  auto stage = [&](int buf, int kk) {
    const int k0 = kk * 64;
    #pragma unroll
    for (int j=0;j<2;++j) {                    // A: 64x64 = 512 transfers
      const int lin = tid + j*256;
      const int r = ((lin>>7)<<4) + (lin&15), kc = ((lin>>4)&7)*8;
      gld_lds16(Ab + (size_t)r*DMOD + k0 + kc, &At[buf][lin*8]);
    }
    #pragma unroll
    for (int j=0;j<2;++j) {                    // B: 64x64 = 512 transfers
      const int lin = tid + j*256;
      const int r = ((lin>>7)<<4) + (lin&15), kc = ((lin>>4)&7)*8;
      gld_lds16(Bb + (size_t)r*DMOD + k0 + kc, &Bt[buf][lin*8]);
    }
  };
  auto compute = [&](int cb) {
    f16x8 af[4], bf[4];
    const int roA = (wm>>4) + (l31>>4);
    const int roB = (wn>>4) + (l31>>4);
    #pragma unroll
    for (int ks=0;ks<4;++ks) {
      af[ks] = *(const f16x8*)(&At[cb][roA*1024 + (ks*2+lhi)*128 + (l31&15)*8]);
      bf[ks] = *(const f16x8*)(&Bt[cb][roB*1024 + (ks*2+lhi)*128 + (l31&15)*8]);
    }
    #pragma unroll
    for (int ks=0;ks<4;++ks)
      acc = __builtin_amdgcn_mfma_f32_32x32x16_f16(af[ks], bf[ks], acc, 0, 0, 0);
  };

  stage(0, 0);
  for (int k = 0; k < 12; ++k) {
    if (k < 11) {
      stage((k+1)%3, k+1);
      asm volatile("s_waitcnt vmcnt(4) lgkmcnt(0)" ::: "memory");
    } else {
      asm volatile("s_waitcnt vmcnt(0) lgkmcnt(0)" ::: "memory");
    }
    __builtin_amdgcn_s_barrier();
    compute(k%3);
  }

  const int col = n0 + wn + l31;
  const float bcol = bo[col];
  const int rb = m0 + wm + 4*lhi;
  #pragma unroll
  for (int g=0; g<16; ++g) {
    const int srow = rb + (g&3) + 8*(g>>2);
    outp[(size_t)srow * DMOD + col] = acc[g] + bcol;
  }
}

// ---------------- banded attention + global-query partials, XCD-swizzled ----------------
// (round-9 verbatim, known passing)
__global__ __launch_bounds__(256) void band_attn(
    const f16* __restrict__ q16, const f16* __restrict__ k16,
    const f16* __restrict__ vt16, f16* __restrict__ att16,
    float* __restrict__ o_part, float* __restrict__ l_part)
{
  __shared__ __align__(16) f16 Pbuf[4][1280];  // 32x40 f16 per wave
  const int bid = blockIdx.x;
  const int wjob = (bid & 7) * 54 + (bid >> 3);
  const int bx = wjob % 36, h = wjob / 36;
  const int tid = threadIdx.x, lane = tid & 63, wid = tid >> 6;
  const int l31 = lane & 31, lhi = lane >> 5;
  f16* P = &Pbuf[wid][0];

  const bool is_gq = (bx >= 32);
  int gr0 = 0, sp = 0, tcount;
  if (is_gq) {
    sp = (bx - 32) * 4 + wid;
    tcount = 8;
  } else {
    const int sub = bx * 4 + wid;
    if (sub == 0) return;                      // rows 0..31 handled by gq path
    gr0 = sub * 32;
    tcount = 10;
  }

  const f16* qh = q16 + (size_t)h * S_LEN * DH;
  const f16* kh = k16 + (size_t)h * S_LEN * DH;
  const f16* vh = vt16 + (size_t)h * DH * S_LEN;

  // Q A-frags: row = gr0 + l31, k(d) = ks*16 + lhi*8
  f16x8 aq[4];
  #pragma unroll
  for (int ks=0;ks<4;++ks)
    aq[ks] = *(const f16x8*)(qh + (size_t)(gr0 + l31)*DH + ks*16 + lhi*8);

  f32x16 accO[2];
  float lacc[16];
  #pragma unroll
  for (int nt=0;nt<2;++nt)
    #pragma unroll
    for (int e=0;e<16;++e) accO[nt][e] = 0.f;
  #pragma unroll
  for (int g=0;g<16;++g) lacc[g] = 0.f;

  for (int t = 0; t < tcount; ++t) {
    int j0;
    if (is_gq) {
      j0 = sp*256 + t*32;
    } else if (t > 0) {
      j0 = gr0 - 128 + (t-1)*32;
      if (j0 <= 0 || j0 >= S_LEN) continue;    // whole-tile j-clip (always aligned)
    } else {
      j0 = 0;                                  // 32 global key columns
    }
    // K B-frags: col(key) = j0 + l31, k(d) = ks*16 + lhi*8
    f16x8 bk[4];
    #pragma unroll
    for (int ks=0;ks<4;++ks)
      bk[ks] = *(const f16x8*)(kh + (size_t)(j0 + l31)*DH + ks*16 + lhi*8);
    f32x16 sc;
    #pragma unroll
    for (int e=0;e<16;++e) sc[e] = 0.f;
    __builtin_amdgcn_s_setprio(1);
    #pragma unroll
    for (int ks=0;ks<4;++ks)
      sc = __builtin_amdgcn_mfma_f32_32x32x16_f16(aq[ks], bk[ks], sc, 0, 0, 0);
    __builtin_amdgcn_s_setprio(0);
    if (!is_gq && (t == 1 || t == 9)) {        // only edge band tiles need masks
      #pragma unroll
      for (int g=0; g<16; ++g) {
        const int r = (g&3) + 8*(g>>2) + 4*lhi;
        const int e = l31 - r;
        const bool ok = (t == 1) ? (e >= 0) : (e <= 0);
        if (!ok) sc[g] = NEGBIG;
      }
    }
    #pragma unroll
    for (int g=0; g<16; ++g) {
      sc[g] = __expf(sc[g]);
      lacc[g] += sc[g];
    }
    // P: C-layout -> LDS -> A-layout (per-wave scratch; in-order DS queue)
    #pragma unroll
    for (int g=0; g<16; ++g)
      P[((g&3) + 8*(g>>2) + 4*lhi)*40 + l31] = (f16)sc[g];
    asm volatile("s_waitcnt lgkmcnt(0)" ::: "memory");
    f16x8 ap[2];
    #pragma unroll
    for (int ks=0;ks<2;++ks)
      ap[ks] = *(const f16x8*)(P + l31*40 + ks*16 + lhi*8);
    // V B-frags: col(d) = nt*32 + l31, k(key) = ks*16 + lhi*8
    f16x8 bvv[2][2];
    #pragma unroll
    for (int nt=0;nt<2;++nt)
      #pragma unroll
      for (int ks=0;ks<2;++ks)
        bvv[nt][ks] = *(const f16x8*)(vh + (size_t)(nt*32 + l31)*S_LEN + j0 + ks*16 + lhi*8);
    __builtin_amdgcn_s_setprio(1);
    #pragma unroll
    for (int nt=0;nt<2;++nt)
      #pragma unroll
      for (int ks=0;ks<2;++ks)
        accO[nt] = __builtin_amdgcn_mfma_f32_32x32x16_f16(ap[ks], bvv[nt][ks], accO[nt], 0, 0, 0);
    __builtin_amdgcn_s_setprio(0);
  }

  // in-wave reduce of l partials across the 32 column-lanes (bits 0..4)
  #pragma unroll
  for (int g=0; g<16; ++g) {
    float v = lacc[g];
    v += __shfl_xor(v, 1, 64);
    v += __shfl_xor(v, 2, 64);
    v += __shfl_xor(v, 4, 64);
    v += __shfl_xor(v, 8, 64);
    v += __shfl_xor(v, 16, 64);
    lacc[g] = v;
  }

  if (is_gq) {
    const int base = (h*16 + sp)*32;
    #pragma unroll
    for (int g=0; g<16; ++g) {
      const int row = (g&3) + 8*(g>>2) + 4*lhi;
      if (l31 == 0) l_part[base+row] = lacc[g];
      #pragma unroll
      for (int nt=0;nt<2;++nt)
        o_part[(size_t)(base+row)*DH + nt*32 + l31] = accO[nt][g];
    }
  } else {
    #pragma unroll
    for (int g=0; g<16; ++g) {
      const float inv = 1.f / lacc[g];
      const int s = gr0 + (g&3) + 8*(g>>2) + 4*lhi;
      #pragma unroll
      for (int nt=0;nt<2;++nt)
        att16[(size_t)s * DMOD + h*DH + nt*32 + l31] = (f16)(accO[nt][g] * inv);
    }
  }
}

__global__ __launch_bounds__(256) void gq_merge(
    const float* __restrict__ o_part, const float* __restrict__ l_part,
    f16* __restrict__ att16)
{
  const int h = blockIdx.x;
  const int t = threadIdx.x;
  for (int u = t; u < 512; u += 256) {
    const int row = u >> 4, c4 = u & 15;
    float4 s = {0.f,0.f,0.f,0.f};
    float l = 0.f;
    for (int sp=0;sp<16;++sp) {
      const int base = (h*16 + sp)*32 + row;
      const float4 v = *(const float4*)&o_part[(size_t)base*DH + c4*4];
      s.x += v.x; s.y += v.y; s.z += v.z; s.w += v.w;
      l += l_part[base];
    }
    const float inv = 1.f / l;
    f16x4 o;
    o[0] = (f16)(s.x*inv); o[1] = (f16)(s.y*inv);
    o[2] = (f16)(s.z*inv); o[3] = (f16)(s.w*inv);
    *(f16x4*)&att16[(size_t)row * DMOD + h*DH + c4*4] = o;
  }
}

extern "C" void kernel_launch(void* const* d_in, const int* in_sizes, int n_in,
                              void* d_out, int out_size, void* d_ws, size_t ws_size,
                              hipStream_t stream)
{
  const float* hs = (const float*)d_in[0];
  const float* Wq = (const float*)d_in[1];
  const float* bq = (const float*)d_in[2];
  const float* Wk = (const float*)d_in[3];
  const float* bk = (const float*)d_in[4];
  const float* Wv = (const float*)d_in[5];
  const float* bv = (const float*)d_in[6];
  const float* Wo = (const float*)d_in[7];
  const float* bo = (const float*)d_in[8];
  float* out = (float*)d_out;
  char* ws = (char*)d_ws;
  f16* h16  = (f16*)(ws + OFF_H16);
  f16* wt   = (f16*)(ws + OFF_WT);
  f16* q16  = (f16*)(ws + OFF_Q);
  f16* k16  = (f16*)(ws + OFF_K);
  f16* vt16 = (f16*)(ws + OFF_VT);
  f16* att16= (f16*)(ws + OFF_ATT);
  float* gqo = (float*)(ws + OFF_GQO);
  float* gql = (float*)(ws + OFF_GQL);

  prep_kernel<<<2112, 256, 0, stream>>>(hs, Wq, Wk, Wv, Wo, h16, wt);
  gemm_qkv<<<576, 256, 0, stream>>>(h16, wt, bq, bk, bv, q16, k16, vt16);
  band_attn<<<432, 256, 0, stream>>>(q16, k16, vt16, att16, gqo, gql);
  gq_merge<<<12, 256, 0, stream>>>(gqo, gql, att16);
  gemm_out<<<768, 256, 0, stream>>>(att16, wt + (size_t)3*DMOD*DMOD, bo, out);
}

// Round 12
// 168.925 us; speedup vs baseline: 1.0422x; 1.0051x over previous
//
#include <hip/hip_runtime.h>
#include <stdint.h>

#define S_LEN 4096
#define DMOD  768
#define NH    12
#define DH    64
#define GG    32
#define NEGBIG (-1e9f)

typedef _Float16 f16;
typedef f16 f16x8 __attribute__((ext_vector_type(8)));
typedef f16 f16x4 __attribute__((ext_vector_type(4)));
typedef float f32x4 __attribute__((ext_vector_type(4)));
typedef float f32x16 __attribute__((ext_vector_type(16)));
typedef uint32_t u32;

// ---------- workspace offsets (bytes), all 256-aligned ----------
#define OFF_H16   ((size_t)0)
#define OFF_WT    ((size_t)6291456)
#define OFF_Q     ((size_t)11010048)
#define OFF_K     ((size_t)17301504)
#define OFF_VT    ((size_t)29884416)
#define OFF_ATT   ((size_t)36175872)
#define OFF_GQO   ((size_t)42467328)
#define OFF_GQL   ((size_t)44040192)

__device__ __forceinline__ void gld_lds16(const void* g, void* l) {
  typedef __attribute__((address_space(3))) u32 lds_u32;
  typedef __attribute__((address_space(1))) u32 glb_u32;
  __builtin_amdgcn_global_load_lds((glb_u32*)(uintptr_t)g,
                                   (lds_u32*)(u32)(uintptr_t)l, 16, 0, 0);
}

// ---------------- prep: weight transpose->f16 + hidden convert ----------------
__global__ __launch_bounds__(256) void prep_kernel(
    const float* __restrict__ hs,
    const float* __restrict__ Wq, const float* __restrict__ Wk,
    const float* __restrict__ Wv, const float* __restrict__ Wo,
    f16* __restrict__ h16, f16* __restrict__ wt)
{
  const int b = blockIdx.x;
  const int t = threadIdx.x;
  if (b < 576) {
    __shared__ float tile[64][65];
    const int w = b / 144, r2 = b % 144;
    const int n0 = (r2 % 12) * 64, k0 = (r2 / 12) * 64;
    const float* W = (w==0) ? Wq : (w==1) ? Wk : (w==2) ? Wv : Wo;
    f16* WT = wt + (size_t)w * DMOD * DMOD;
    #pragma unroll
    for (int rnd = 0; rnd < 4; ++rnd) {
      const int lin = rnd * 1024 + t * 4;
      const int r = lin >> 6, c = lin & 63;
      const float4 vv = *(const float4*)(W + (size_t)(k0 + r) * DMOD + n0 + c);
      tile[r][c+0] = vv.x; tile[r][c+1] = vv.y; tile[r][c+2] = vv.z; tile[r][c+3] = vv.w;
    }
    __syncthreads();
    #pragma unroll
    for (int rnd = 0; rnd < 2; ++rnd) {
      const int lin = rnd * 256 + t;
      const int n = lin >> 3, kc = (lin & 7) * 8;
      f16x8 o;
      #pragma unroll
      for (int j = 0; j < 8; ++j) o[j] = (f16)tile[kc + j][n];
      *(f16x8*)(WT + (size_t)(n0 + n) * DMOD + k0 + kc) = o;
    }
  } else {
    const size_t idx = (size_t)(b - 576) * 2048 + (size_t)t * 8;
    const float4 a = *(const float4*)(hs + idx);
    const float4 c = *(const float4*)(hs + idx + 4);
    f16x8 o;
    o[0]=(f16)a.x; o[1]=(f16)a.y; o[2]=(f16)a.z; o[3]=(f16)a.w;
    o[4]=(f16)c.x; o[5]=(f16)c.y; o[6]=(f16)c.z; o[7]=(f16)c.w;
    *(f16x8*)(h16 + idx) = o;
  }
}

// ---------------- QKV projection GEMM: Round-2 configuration VERBATIM (42.6 us best) ---------
// 128x128 tile, triple-buffered LDS, stage(nxt)->vmcnt(4)->barrier->compute(cur),
// 8 MFMA/wave/iter, dim3(6,32,3) grid, NO swizzle — the fastest measured variant.
// (Swizzled 1-D variants of the same body measured 44.0-45.8 us; default
// round-robin dispatch spreads same-A-panel blocks across XCDs, avoiding bursty
// same-panel L2 contention.)
__global__ __launch_bounds__(256) void gemm_qkv(
    const f16* __restrict__ A, const f16* __restrict__ wt,
    const float* __restrict__ bq, const float* __restrict__ bk, const float* __restrict__ bv,
    f16* __restrict__ q16, f16* __restrict__ k16, f16* __restrict__ vt16)
{
  __shared__ __align__(16) f16 At[3][4096];
  __shared__ __align__(16) f16 Bt[3][4096];
  const int z = blockIdx.z;
  const f16* Wt = wt + (size_t)z * DMOD * DMOD;
  const float* bias = (z==0) ? bq : (z==1) ? bk : bv;
  const float scale = (z==0) ? 0.125f : 1.0f;

  const int tid = threadIdx.x;
  const int lane = tid & 63, wid = tid >> 6;
  const int l31 = lane & 31, lhi = lane >> 5;
  const int n0 = blockIdx.x * 128, m0 = blockIdx.y * 128;
  const int wm = (wid >> 1) * 64, wn = (wid & 1) * 64;

  f32x16 acc[2][2];
  #pragma unroll
  for (int i=0;i<2;++i)
    #pragma unroll
    for (int j=0;j<2;++j)
      #pragma unroll
      for (int e=0;e<16;++e) acc[i][j][e] = 0.f;

  const int lin0 = tid, lin1 = tid + 256;
  const int ar0 = ((lin0>>6)<<4) + (lin0&15), ac0 = ((lin0>>4)&3)*8;
  const int ar1 = ((lin1>>6)<<4) + (lin1&15), ac1 = ((lin1>>4)&3)*8;
  const f16* Ab = A  + (size_t)m0 * DMOD;
  const f16* Bb = Wt + (size_t)n0 * DMOD;

  // prologue: stage k-chunk 0 into buffer 0
  gld_lds16(Ab + (size_t)ar0*DMOD + ac0, &At[0][lin0*8]);
  gld_lds16(Ab + (size_t)ar1*DMOD + ac1, &At[0][lin1*8]);
  gld_lds16(Bb + (size_t)ar0*DMOD + ac0, &Bt[0][lin0*8]);
  gld_lds16(Bb + (size_t)ar1*DMOD + ac1, &Bt[0][lin1*8]);

  int cur = 0;
  #pragma unroll 3
  for (int k = 0; k < 24; ++k) {
    const int nxt = (cur == 2) ? 0 : cur + 1;
    if (k < 23) {
      const int k0 = (k + 1) * 32;
      gld_lds16(Ab + (size_t)ar0*DMOD + k0 + ac0, &At[nxt][lin0*8]);
      gld_lds16(Ab + (size_t)ar1*DMOD + k0 + ac1, &At[nxt][lin1*8]);
      gld_lds16(Bb + (size_t)ar0*DMOD + k0 + ac0, &Bt[nxt][lin0*8]);
      gld_lds16(Bb + (size_t)ar1*DMOD + k0 + ac1, &Bt[nxt][lin1*8]);
      asm volatile("s_waitcnt vmcnt(4) lgkmcnt(0)" ::: "memory");
    } else {
      asm volatile("s_waitcnt vmcnt(0) lgkmcnt(0)" ::: "memory");
    }
    __builtin_amdgcn_s_barrier();
    // A-frag (32x32x16): row = R0 + l31, k = ks*16 + lhi*8
    // LDS hw addr(r,k) = (r>>4)*512 + (k>>3)*128 + (r&15)*8
    f16x8 af[2][2], bf[2][2];
    #pragma unroll
    for (int mi=0;mi<2;++mi)
      #pragma unroll
      for (int ks=0;ks<2;++ks) {
        const int ro = (wm>>4) + mi*2 + (l31>>4);
        af[mi][ks] = *(const f16x8*)(&At[cur][ro*512 + (ks*2+lhi)*128 + (l31&15)*8]);
      }
    #pragma unroll
    for (int nj=0;nj<2;++nj)
      #pragma unroll
      for (int ks=0;ks<2;++ks) {
        const int ro = (wn>>4) + nj*2 + (l31>>4);
        bf[nj][ks] = *(const f16x8*)(&Bt[cur][ro*512 + (ks*2+lhi)*128 + (l31&15)*8]);
      }
    #pragma unroll
    for (int mi=0;mi<2;++mi)
      #pragma unroll
      for (int nj=0;nj<2;++nj) {
        acc[mi][nj] = __builtin_amdgcn_mfma_f32_32x32x16_f16(af[mi][0], bf[nj][0], acc[mi][nj], 0, 0, 0);
        acc[mi][nj] = __builtin_amdgcn_mfma_f32_32x32x16_f16(af[mi][1], bf[nj][1], acc[mi][nj], 0, 0, 0);
      }
    cur = nxt;
  }

  if (z < 2) {
    f16* outp = (z==0) ? q16 : k16;
    #pragma unroll
    for (int nj=0;nj<2;++nj) {
      const int col = n0 + wn + nj*32 + l31;
      const float bcol = bias[col];
      const int hh = col >> 6, d = col & 63;
      f16* dcol = outp + (size_t)hh * S_LEN * DH + d;
      #pragma unroll
      for (int mi=0;mi<2;++mi) {
        const int rb = m0 + wm + mi*32 + 4*lhi;
        #pragma unroll
        for (int g=0; g<16; ++g) {
          const int srow = rb + (g&3) + 8*(g>>2);
          dcol[(size_t)srow * DH] = (f16)((acc[mi][nj][g] + bcol) * scale);
        }
      }
    }
  } else {
    #pragma unroll
    for (int nj=0;nj<2;++nj) {
      const int col = n0 + wn + nj*32 + l31;
      const float bcol = bias[col];
      const int hh = col >> 6, d = col & 63;
      f16* dcol = vt16 + ((size_t)hh * DH + d) * S_LEN;
      #pragma unroll
      for (int mi=0;mi<2;++mi) {
        const int rb = m0 + wm + mi*32 + 4*lhi;
        #pragma unroll
        for (int q4=0;q4<4;++q4) {
          f16x4 o;
          #pragma unroll
          for (int r=0;r<4;++r) o[r] = (f16)(acc[mi][nj][q4*4+r] + bcol);
          *(f16x4*)(dcol + rb + 8*q4) = o;
        }
      }
    }
  }
}

// ---------------- output GEMM, BK=64, 12 iters, 64x64 tiles, XCD-swizzled ----------------
// (round-11 verbatim, known passing)
__global__ __launch_bounds__(256) void gemm_out(
    const f16* __restrict__ A, const f16* __restrict__ Wt,
    const float* __restrict__ bo, float* __restrict__ outp)
{
  __shared__ __align__(16) f16 At[3][4096];
  __shared__ __align__(16) f16 Bt[3][4096];
  const int bid = blockIdx.x;
  const int w = (bid & 7) * 96 + (bid >> 3);
  const int x = w % 12, y = w / 12;
  const int tid = threadIdx.x;
  const int lane = tid & 63, wid = tid >> 6;
  const int l31 = lane & 31, lhi = lane >> 5;
  const int n0 = x * 64, m0 = y * 64;
  const int wm = (wid >> 1) * 32, wn = (wid & 1) * 32;

  f32x16 acc;
  #pragma unroll
  for (int e=0;e<16;++e) acc[e] = 0.f;

  const f16* Ab = A  + (size_t)m0 * DMOD;
  const f16* Bb = Wt + (size_t)n0 * DMOD;

  auto stage = [&](int buf, int kk) {
    const int k0 = kk * 64;
    #pragma unroll
    for (int j=0;j<2;++j) {                    // A: 64x64 = 512 transfers
      const int lin = tid + j*256;
      const int r = ((lin>>7)<<4) + (lin&15), kc = ((lin>>4)&7)*8;
      gld_lds16(Ab + (size_t)r*DMOD + k0 + kc, &At[buf][lin*8]);
    }
    #pragma unroll
    for (int j=0;j<2;++j) {                    // B: 64x64 = 512 transfers
      const int lin = tid + j*256;
      const int r = ((lin>>7)<<4) + (lin&15), kc = ((lin>>4)&7)*8;
      gld_lds16(Bb + (size_t)r*DMOD + k0 + kc, &Bt[buf][lin*8]);
    }
  };
  auto compute = [&](int cb) {
    f16x8 af[4], bf[4];
    const int roA = (wm>>4) + (l31>>4);
    const int roB = (wn>>4) + (l31>>4);
    #pragma unroll
    for (int ks=0;ks<4;++ks) {
      af[ks] = *(const f16x8*)(&At[cb][roA*1024 + (ks*2+lhi)*128 + (l31&15)*8]);
      bf[ks] = *(const f16x8*)(&Bt[cb][roB*1024 + (ks*2+lhi)*128 + (l31&15)*8]);
    }
    #pragma unroll
    for (int ks=0;ks<4;++ks)
      acc = __builtin_amdgcn_mfma_f32_32x32x16_f16(af[ks], bf[ks], acc, 0, 0, 0);
  };

  stage(0, 0);
  for (int k = 0; k < 12; ++k) {
    if (k < 11) {
      stage((k+1)%3, k+1);
      asm volatile("s_waitcnt vmcnt(4) lgkmcnt(0)" ::: "memory");
    } else {
      asm volatile("s_waitcnt vmcnt(0) lgkmcnt(0)" ::: "memory");
    }
    __builtin_amdgcn_s_barrier();
    compute(k%3);
  }

  const int col = n0 + wn + l31;
  const float bcol = bo[col];
  const int rb = m0 + wm + 4*lhi;
  #pragma unroll
  for (int g=0; g<16; ++g) {
    const int srow = rb + (g&3) + 8*(g>>2);
    outp[(size_t)srow * DMOD + col] = acc[g] + bcol;
  }
}

// ---------------- banded attention + global-query partials, XCD-swizzled ----------------
// (round-11 verbatim, known passing)
__global__ __launch_bounds__(256) void band_attn(
    const f16* __restrict__ q16, const f16* __restrict__ k16,
    const f16* __restrict__ vt16, f16* __restrict__ att16,
    float* __restrict__ o_part, float* __restrict__ l_part)
{
  __shared__ __align__(16) f16 Pbuf[4][1280];  // 32x40 f16 per wave
  const int bid = blockIdx.x;
  const int wjob = (bid & 7) * 54 + (bid >> 3);
  const int bx = wjob % 36, h = wjob / 36;
  const int tid = threadIdx.x, lane = tid & 63, wid = tid >> 6;
  const int l31 = lane & 31, lhi = lane >> 5;
  f16* P = &Pbuf[wid][0];

  const bool is_gq = (bx >= 32);
  int gr0 = 0, sp = 0, tcount;
  if (is_gq) {
    sp = (bx - 32) * 4 + wid;
    tcount = 8;
  } else {
    const int sub = bx * 4 + wid;
    if (sub == 0) return;                      // rows 0..31 handled by gq path
    gr0 = sub * 32;
    tcount = 10;
  }

  const f16* qh = q16 + (size_t)h * S_LEN * DH;
  const f16* kh = k16 + (size_t)h * S_LEN * DH;
  const f16* vh = vt16 + (size_t)h * DH * S_LEN;

  // Q A-frags: row = gr0 + l31, k(d) = ks*16 + lhi*8
  f16x8 aq[4];
  #pragma unroll
  for (int ks=0;ks<4;++ks)
    aq[ks] = *(const f16x8*)(qh + (size_t)(gr0 + l31)*DH + ks*16 + lhi*8);

  f32x16 accO[2];
  float lacc[16];
  #pragma unroll
  for (int nt=0;nt<2;++nt)
    #pragma unroll
    for (int e=0;e<16;++e) accO[nt][e] = 0.f;
  #pragma unroll
  for (int g=0;g<16;++g) lacc[g] = 0.f;

  for (int t = 0; t < tcount; ++t) {
    int j0;
    if (is_gq) {
      j0 = sp*256 + t*32;
    } else if (t > 0) {
      j0 = gr0 - 128 + (t-1)*32;
      if (j0 <= 0 || j0 >= S_LEN) continue;    // whole-tile j-clip (always aligned)
    } else {
      j0 = 0;                                  // 32 global key columns
    }
    // K B-frags: col(key) = j0 + l31, k(d) = ks*16 + lhi*8
    f16x8 bk[4];
    #pragma unroll
    for (int ks=0;ks<4;++ks)
      bk[ks] = *(const f16x8*)(kh + (size_t)(j0 + l31)*DH + ks*16 + lhi*8);
    f32x16 sc;
    #pragma unroll
    for (int e=0;e<16;++e) sc[e] = 0.f;
    __builtin_amdgcn_s_setprio(1);
    #pragma unroll
    for (int ks=0;ks<4;++ks)
      sc = __builtin_amdgcn_mfma_f32_32x32x16_f16(aq[ks], bk[ks], sc, 0, 0, 0);
    __builtin_amdgcn_s_setprio(0);
    if (!is_gq && (t == 1 || t == 9)) {        // only edge band tiles need masks
      #pragma unroll
      for (int g=0; g<16; ++g) {
        const int r = (g&3) + 8*(g>>2) + 4*lhi;
        const int e = l31 - r;
        const bool ok = (t == 1) ? (e >= 0) : (e <= 0);
        if (!ok) sc[g] = NEGBIG;
      }
    }
    #pragma unroll
    for (int g=0; g<16; ++g) {
      sc[g] = __expf(sc[g]);
      lacc[g] += sc[g];
    }
    // P: C-layout -> LDS -> A-layout (per-wave scratch; in-order DS queue)
    #pragma unroll
    for (int g=0; g<16; ++g)
      P[((g&3) + 8*(g>>2) + 4*lhi)*40 + l31] = (f16)sc[g];
    asm volatile("s_waitcnt lgkmcnt(0)" ::: "memory");
    f16x8 ap[2];
    #pragma unroll
    for (int ks=0;ks<2;++ks)
      ap[ks] = *(const f16x8*)(P + l31*40 + ks*16 + lhi*8);
    // V B-frags: col(d) = nt*32 + l31, k(key) = ks*16 + lhi*8
    f16x8 bvv[2][2];
    #pragma unroll
    for (int nt=0;nt<2;++nt)
      #pragma unroll
      for (int ks=0;ks<2;++ks)
        bvv[nt][ks] = *(const f16x8*)(vh + (size_t)(nt*32 + l31)*S_LEN + j0 + ks*16 + lhi*8);
    __builtin_amdgcn_s_setprio(1);
    #pragma unroll
    for (int nt=0;nt<2;++nt)
      #pragma unroll
      for (int ks=0;ks<2;++ks)
        accO[nt] = __builtin_amdgcn_mfma_f32_32x32x16_f16(ap[ks], bvv[nt][ks], accO[nt], 0, 0, 0);
    __builtin_amdgcn_s_setprio(0);
  }

  // in-wave reduce of l partials across the 32 column-lanes (bits 0..4)
  #pragma unroll
  for (int g=0; g<16; ++g) {
    float v = lacc[g];
    v += __shfl_xor(v, 1, 64);
    v += __shfl_xor(v, 2, 64);
    v += __shfl_xor(v, 4, 64);
    v += __shfl_xor(v, 8, 64);
    v += __shfl_xor(v, 16, 64);
    lacc[g] = v;
  }

  if (is_gq) {
    const int base = (h*16 + sp)*32;
    #pragma unroll
    for (int g=0; g<16; ++g) {
      const int row = (g&3) + 8*(g>>2) + 4*lhi;
      if (l31 == 0) l_part[base+row] = lacc[g];
      #pragma unroll
      for (int nt=0;nt<2;++nt)
        o_part[(size_t)(base+row)*DH + nt*32 + l31] = accO[nt][g];
    }
  } else {
    #pragma unroll
    for (int g=0; g<16; ++g) {
      const float inv = 1.f / lacc[g];
      const int s = gr0 + (g&3) + 8*(g>>2) + 4*lhi;
      #pragma unroll
      for (int nt=0;nt<2;++nt)
        att16[(size_t)s * DMOD + h*DH + nt*32 + l31] = (f16)(accO[nt][g] * inv);
    }
  }
}

__global__ __launch_bounds__(256) void gq_merge(
    const float* __restrict__ o_part, const float* __restrict__ l_part,
    f16* __restrict__ att16)
{
  const int h = blockIdx.x;
  const int t = threadIdx.x;
  for (int u = t; u < 512; u += 256) {
    const int row = u >> 4, c4 = u & 15;
    float4 s = {0.f,0.f,0.f,0.f};
    float l = 0.f;
    for (int sp=0;sp<16;++sp) {
      const int base = (h*16 + sp)*32 + row;
      const float4 v = *(const float4*)&o_part[(size_t)base*DH + c4*4];
      s.x += v.x; s.y += v.y; s.z += v.z; s.w += v.w;
      l += l_part[base];
    }
    const float inv = 1.f / l;
    f16x4 o;
    o[0] = (f16)(s.x*inv); o[1] = (f16)(s.y*inv);
    o[2] = (f16)(s.z*inv); o[3] = (f16)(s.w*inv);
    *(f16x4*)&att16[(size_t)row * DMOD + h*DH + c4*4] = o;
  }
}

extern "C" void kernel_launch(void* const* d_in, const int* in_sizes, int n_in,
                              void* d_out, int out_size, void* d_ws, size_t ws_size,
                              hipStream_t stream)
{
  const float* hs = (const float*)d_in[0];
  const float* Wq = (const float*)d_in[1];
  const float* bq = (const float*)d_in[2];
  const float* Wk = (const float*)d_in[3];
  const float* bk = (const float*)d_in[4];
  const float* Wv = (const float*)d_in[5];
  const float* bv = (const float*)d_in[6];
  const float* Wo = (const float*)d_in[7];
  const float* bo = (const float*)d_in[8];
  float* out = (float*)d_out;
  char* ws = (char*)d_ws;
  f16* h16  = (f16*)(ws + OFF_H16);
  f16* wt   = (f16*)(ws + OFF_WT);
  f16* q16  = (f16*)(ws + OFF_Q);
  f16* k16  = (f16*)(ws + OFF_K);
  f16* vt16 = (f16*)(ws + OFF_VT);
  f16* att16= (f16*)(ws + OFF_ATT);
  float* gqo = (float*)(ws + OFF_GQO);
  float* gql = (float*)(ws + OFF_GQL);

  prep_kernel<<<2112, 256, 0, stream>>>(hs, Wq, Wk, Wv, Wo, h16, wt);
  gemm_qkv<<<dim3(6,32,3), 256, 0, stream>>>(h16, wt, bq, bk, bv, q16, k16, vt16);
  band_attn<<<432, 256, 0, stream>>>(q16, k16, vt16, att16, gqo, gql);
  gq_merge<<<12, 256, 0, stream>>>(gqo, gql, att16);
  gemm_out<<<768, 256, 0, stream>>>(att16, wt + (size_t)3*DMOD*DMOD, bo, out);
}